// Round 7
// baseline (455434.131 us; speedup 1.0000x reference)
//
#include <hip/hip_runtime.h>
#include <hip/hip_bf16.h>

#define L_CLS 2048
#define D_DIM 512
#define T_SZ  512
#define NT    511              // T-1 transitions per sequence
#define NOUT  (64 * NT)        // 32704
#define NCHUNK 32              // 64-col chunks
#define NWG   512              // 2 blocks/CU on 256 CUs -> all co-resident
#define LDS_STRIDE 136         // 128 bf16 + pad -> 272 B rows
#define LOG2E 1.4426950408889634f
#define LN2   0.6931471805599453f
#define SHIFT 128.0f           // fixed exponent shift: sum 2^(x*log2e - SHIFT)

typedef __attribute__((ext_vector_type(8))) short bf16x8;
typedef __attribute__((ext_vector_type(4))) float f32x4;

static __device__ __forceinline__ short f2bf(float x) {
    return (short)__bfloat16_as_ushort(__float2bfloat16(x));
}

// One kernel, three phases:
//  P1 (per WG w: bx=w>>5, by=w&31): stage 64-col T-chunk f32->bf16 in LDS per
//     K-slice; two 64-row S-blocks (bx, bx+16) of MFMAs with B-frags hoisted
//     across row-blocks (halves ds_read traffic). Write logits tile to M and
//     fixed-shift exp partial sums to psum.
//  Epoch-free grid spin-barrier (all 512 WGs co-resident by construction;
//     works for ANY initial cnt/rel value: each call adds exactly 512 arrivals
//     and 512 | 2^32, so exactly one arrival satisfies (old+1)%512==0).
//  P3: 64 outputs per WG: out = M[src,tgt] - (log2(sum psum[src,:]) + SHIFT)*ln2.
//     M/psum read volatile (L1-bypass) after device-scope fence.
__launch_bounds__(256, 2)
__global__ void fused_crf(const int* __restrict__ labels,
                          const float* __restrict__ srcE,
                          const float* __restrict__ tgtE,
                          float* psum, float* M,
                          unsigned* cnt, unsigned* rel,
                          float* __restrict__ out, int useM) {
    __shared__ __hip_bfloat16 Blds[64 * LDS_STRIDE];   // 17408 B

    const int w    = blockIdx.x;
    const int tid  = threadIdx.x;
    const int wave = tid >> 6;
    const int lane = tid & 63;
    const int lr   = lane & 15;
    const int hi   = lane >> 4;
    const int by   = w & 31;
    const int bx   = w >> 5;
    const int C    = by * 64;
    const int R0   = bx * 64 + wave * 16;            // row-block 0
    const int R1   = (bx + 16) * 64 + wave * 16;     // row-block 1

    f32x4 acc[2][4];
#pragma unroll
    for (int rb = 0; rb < 2; ++rb)
#pragma unroll
        for (int ct = 0; ct < 4; ++ct) acc[rb][ct] = (f32x4){0.f, 0.f, 0.f, 0.f};

#pragma unroll
    for (int s = 0; s < 4; ++s) {    // K-slices of 128
        // ---- stage 64 rows x 128 k of T chunk into LDS (f32 -> bf16) ----
#pragma unroll
        for (int i = 0; i < 4; ++i) {
            int p   = tid + 256 * i;         // 0..1023
            int row = p >> 4;                // 0..63
            int grp = p & 15;                // 8-elem group 0..15
            const f32x4* g = reinterpret_cast<const f32x4*>(
                tgtE + (C + row) * D_DIM + s * 128 + grp * 8);
            f32x4 x0 = g[0], x1 = g[1];
            bf16x8 v;
#pragma unroll
            for (int e = 0; e < 4; ++e) { v[e] = f2bf(x0[e]); v[e + 4] = f2bf(x1[e]); }
            *reinterpret_cast<bf16x8*>(&Blds[row * LDS_STRIDE + grp * 8]) = v;
        }
        __syncthreads();

        // ---- A fragments for BOTH row-blocks, this slice (regs) ----
        bf16x8 a[2][4];
#pragma unroll
        for (int rb = 0; rb < 2; ++rb) {
            const int R = rb ? R1 : R0;
            const float* arow = srcE + (R + lr) * D_DIM + s * 128 + hi * 8;
#pragma unroll
            for (int ks = 0; ks < 4; ++ks) {
                const f32x4* g = reinterpret_cast<const f32x4*>(arow + ks * 32);
                f32x4 x0 = g[0], x1 = g[1];
                bf16x8 v;
#pragma unroll
                for (int e = 0; e < 4; ++e) { v[e] = f2bf(x0[e]); v[e + 4] = f2bf(x1[e]); }
                a[rb][ks] = v;
            }
        }

        // ---- MFMAs: B fragment loaded ONCE, used by both row-blocks ----
#pragma unroll
        for (int ks = 0; ks < 4; ++ks) {
            const int off = ks * 32 + hi * 8;
            bf16x8 b0 = *reinterpret_cast<const bf16x8*>(&Blds[(0*16 + lr) * LDS_STRIDE + off]);
            bf16x8 b1 = *reinterpret_cast<const bf16x8*>(&Blds[(1*16 + lr) * LDS_STRIDE + off]);
            bf16x8 b2 = *reinterpret_cast<const bf16x8*>(&Blds[(2*16 + lr) * LDS_STRIDE + off]);
            bf16x8 b3 = *reinterpret_cast<const bf16x8*>(&Blds[(3*16 + lr) * LDS_STRIDE + off]);
            acc[0][0] = __builtin_amdgcn_mfma_f32_16x16x32_bf16(a[0][ks], b0, acc[0][0], 0, 0, 0);
            acc[1][0] = __builtin_amdgcn_mfma_f32_16x16x32_bf16(a[1][ks], b0, acc[1][0], 0, 0, 0);
            acc[0][1] = __builtin_amdgcn_mfma_f32_16x16x32_bf16(a[0][ks], b1, acc[0][1], 0, 0, 0);
            acc[1][1] = __builtin_amdgcn_mfma_f32_16x16x32_bf16(a[1][ks], b1, acc[1][1], 0, 0, 0);
            acc[0][2] = __builtin_amdgcn_mfma_f32_16x16x32_bf16(a[0][ks], b2, acc[0][2], 0, 0, 0);
            acc[1][2] = __builtin_amdgcn_mfma_f32_16x16x32_bf16(a[1][ks], b2, acc[1][2], 0, 0, 0);
            acc[0][3] = __builtin_amdgcn_mfma_f32_16x16x32_bf16(a[0][ks], b3, acc[0][3], 0, 0, 0);
            acc[1][3] = __builtin_amdgcn_mfma_f32_16x16x32_bf16(a[1][ks], b3, acc[1][3], 0, 0, 0);
        }
        __syncthreads();
    }

    // ---- epilogue: M writes + fixed-shift exp sums ----
    // D layout: col = C + ct*16 + lr, row = R + hi*4 + i.
#pragma unroll
    for (int rb = 0; rb < 2; ++rb) {
        const int R = rb ? R1 : R0;
        if (useM) {
#pragma unroll
            for (int i = 0; i < 4; ++i) {
                size_t rg = (size_t)(R + hi * 4 + i) * L_CLS + C + lr;
                M[rg]      = acc[rb][0][i];
                M[rg + 16] = acc[rb][1][i];
                M[rg + 32] = acc[rb][2][i];
                M[rg + 48] = acc[rb][3][i];
            }
        }
        float p[4];
#pragma unroll
        for (int i = 0; i < 4; ++i) {
            p[i] = exp2f(acc[rb][0][i] * LOG2E - SHIFT)
                 + exp2f(acc[rb][1][i] * LOG2E - SHIFT)
                 + exp2f(acc[rb][2][i] * LOG2E - SHIFT)
                 + exp2f(acc[rb][3][i] * LOG2E - SHIFT);
        }
#pragma unroll
        for (int off = 1; off < 16; off <<= 1)
#pragma unroll
            for (int i = 0; i < 4; ++i) p[i] += __shfl_xor(p[i], off);
        if (lr == 0) {
#pragma unroll
            for (int i = 0; i < 4; ++i)
                psum[(R + hi * 4 + i) * NCHUNK + by] = p[i];
        }
    }

    // ---- epoch-free grid barrier ----
    __threadfence();              // release: M/psum visible device-wide
    __syncthreads();
    if (tid == 0) {
        unsigned r0  = atomicAdd(rel, 0u);           // pre-arrival snapshot
        unsigned old = atomicAdd(cnt, 1u);
        if (((old + 1u) & (NWG - 1u)) == 0u) {
            atomicAdd(rel, 1u);                      // I'm the 512th arrival
        } else {
            volatile unsigned* vr = rel;
            unsigned guard = 0;
            while (*vr == r0 && ++guard < (1u << 22)) {}   // bounded spin
        }
    }
    __syncthreads();
    __threadfence();              // acquire

    // ---- P3: scores (64 outputs per WG, threads 0..63) ----
    if (tid < 64) {
        int o = w * 64 + tid;
        if (o < NOUT) {
            int b = o / NT;
            int t = o - b * NT;
            int src = labels[b * T_SZ + t];
            int tgt = labels[b * T_SZ + t + 1];

            volatile const float* pv = psum + src * NCHUNK;
            float S = 0.f;
#pragma unroll
            for (int c = 0; c < NCHUNK; ++c) S += pv[c];
            float lse = (log2f(S) + SHIFT) * LN2;

            float logit;
            if (useM) {
                volatile const float* mv = M + (size_t)src * L_CLS + tgt;
                logit = *mv;
            } else {
                const f32x4* sp = reinterpret_cast<const f32x4*>(srcE + src * D_DIM);
                const f32x4* tp = reinterpret_cast<const f32x4*>(tgtE + tgt * D_DIM);
                float a2 = 0.f;
                for (int j = 0; j < D_DIM / 4; ++j) {
                    f32x4 sv = sp[j], tv = tp[j];
                    a2 += sv[0]*tv[0] + sv[1]*tv[1] + sv[2]*tv[2] + sv[3]*tv[3];
                }
                logit = a2;
            }
            out[o] = logit - lse;
        }
    }
}

// ------------------------------------------------------------------- launcher
extern "C" void kernel_launch(void* const* d_in, const int* in_sizes, int n_in,
                              void* d_out, int out_size, void* d_ws, size_t ws_size,
                              hipStream_t stream) {
    const int*   labels = (const int*)d_in[0];
    const float* srcE   = (const float*)d_in[1];
    const float* tgtE   = (const float*)d_in[2];
    float*       out    = (float*)d_out;

    unsigned* cnt = (unsigned*)d_ws;
    unsigned* rel = cnt + 1;
    float* psum = (float*)((char*)d_ws + 16);          // 256 KB
    float* M    = psum + L_CLS * NCHUNK;               // 16 MB

    size_t need = 16 + ((size_t)L_CLS * NCHUNK + (size_t)L_CLS * L_CLS) * sizeof(float);
    int useM = (ws_size >= need) ? 1 : 0;

    fused_crf<<<NWG, 256, 0, stream>>>(labels, srcE, tgtE, psum, M, cnt, rel, out, useM);
}

// Round 8
// 7185.388 us; speedup vs baseline: 63.3834x; 63.3834x over previous
//
#include <hip/hip_runtime.h>
#include <hip/hip_bf16.h>

#define L_CLS 2048
#define D_DIM 512
#define T_SZ  512
#define NT    511              // T-1 transitions per sequence
#define NOUT  (64 * NT)        // 32704
#define NCHUNK 32              // 64-col chunks
#define NWG   512              // 2 blocks/CU on 256 CUs -> all co-resident
#define LDS_STRIDE 136         // 128 bf16 + pad -> 272 B rows
#define LOG2E 1.4426950408889634f
#define LN2   0.6931471805599453f
#define SHIFT 128.0f           // fixed exponent shift: sum 2^(x*log2e - SHIFT)

typedef __attribute__((ext_vector_type(8))) short bf16x8;
typedef __attribute__((ext_vector_type(4))) float f32x4;

static __device__ __forceinline__ short f2bf(float x) {
    return (short)__bfloat16_as_ushort(__float2bfloat16(x));
}

// One kernel, three phases:
//  P1 (per WG w: bx=w>>5, by=w&31): stage 64-col T-chunk f32->bf16 in LDS per
//     K-slice; two 64-row S-blocks (bx, bx+16) of MFMAs with B-frags hoisted
//     across row-blocks. Write logits tile to M + fixed-shift exp sums to psum.
//  Epoch-free grid spin-barrier. Cross-XCD correctness: arrival/release via
//     device-scope atomics; the SPIN READ must be an agent-scope atomic load
//     (plain/volatile loads hit the spinner's own per-XCD L2 and never see the
//     release -- measured 455 ms guard-exhaustion in R7). Epoch-free: each call
//     adds exactly NWG arrivals and NWG | 2^32, so any initial cnt value
//     (0xAA poison, leftovers) still yields exactly one releaser per call.
//  P3: 64 outputs per WG: out = M[src,tgt] - (log2(sum psum[src,:]) + SHIFT)*ln2.
__launch_bounds__(256, 2)
__global__ void fused_crf(const int* __restrict__ labels,
                          const float* __restrict__ srcE,
                          const float* __restrict__ tgtE,
                          float* psum, float* M,
                          unsigned* cnt, unsigned* rel,
                          float* __restrict__ out, int useM) {
    __shared__ __hip_bfloat16 Blds[64 * LDS_STRIDE];   // 17408 B

    const int w    = blockIdx.x;
    const int tid  = threadIdx.x;
    const int wave = tid >> 6;
    const int lane = tid & 63;
    const int lr   = lane & 15;
    const int hi   = lane >> 4;
    const int by   = w & 31;
    const int bx   = w >> 5;
    const int C    = by * 64;
    const int R0   = bx * 64 + wave * 16;            // row-block 0
    const int R1   = (bx + 16) * 64 + wave * 16;     // row-block 1

    f32x4 acc[2][4];
#pragma unroll
    for (int rb = 0; rb < 2; ++rb)
#pragma unroll
        for (int ct = 0; ct < 4; ++ct) acc[rb][ct] = (f32x4){0.f, 0.f, 0.f, 0.f};

#pragma unroll
    for (int s = 0; s < 4; ++s) {    // K-slices of 128
        // ---- stage 64 rows x 128 k of T chunk into LDS (f32 -> bf16) ----
#pragma unroll
        for (int i = 0; i < 4; ++i) {
            int p   = tid + 256 * i;         // 0..1023
            int row = p >> 4;                // 0..63
            int grp = p & 15;                // 8-elem group 0..15
            const f32x4* g = reinterpret_cast<const f32x4*>(
                tgtE + (C + row) * D_DIM + s * 128 + grp * 8);
            f32x4 x0 = g[0], x1 = g[1];
            bf16x8 v;
#pragma unroll
            for (int e = 0; e < 4; ++e) { v[e] = f2bf(x0[e]); v[e + 4] = f2bf(x1[e]); }
            *reinterpret_cast<bf16x8*>(&Blds[row * LDS_STRIDE + grp * 8]) = v;
        }
        __syncthreads();

        // ---- A fragments for BOTH row-blocks, this slice (regs) ----
        bf16x8 a[2][4];
#pragma unroll
        for (int rb = 0; rb < 2; ++rb) {
            const int R = rb ? R1 : R0;
            const float* arow = srcE + (R + lr) * D_DIM + s * 128 + hi * 8;
#pragma unroll
            for (int ks = 0; ks < 4; ++ks) {
                const f32x4* g = reinterpret_cast<const f32x4*>(arow + ks * 32);
                f32x4 x0 = g[0], x1 = g[1];
                bf16x8 v;
#pragma unroll
                for (int e = 0; e < 4; ++e) { v[e] = f2bf(x0[e]); v[e + 4] = f2bf(x1[e]); }
                a[rb][ks] = v;
            }
        }

        // ---- MFMAs: B fragment loaded ONCE, used by both row-blocks ----
#pragma unroll
        for (int ks = 0; ks < 4; ++ks) {
            const int off = ks * 32 + hi * 8;
            bf16x8 b0 = *reinterpret_cast<const bf16x8*>(&Blds[(0*16 + lr) * LDS_STRIDE + off]);
            bf16x8 b1 = *reinterpret_cast<const bf16x8*>(&Blds[(1*16 + lr) * LDS_STRIDE + off]);
            bf16x8 b2 = *reinterpret_cast<const bf16x8*>(&Blds[(2*16 + lr) * LDS_STRIDE + off]);
            bf16x8 b3 = *reinterpret_cast<const bf16x8*>(&Blds[(3*16 + lr) * LDS_STRIDE + off]);
            acc[0][0] = __builtin_amdgcn_mfma_f32_16x16x32_bf16(a[0][ks], b0, acc[0][0], 0, 0, 0);
            acc[1][0] = __builtin_amdgcn_mfma_f32_16x16x32_bf16(a[1][ks], b0, acc[1][0], 0, 0, 0);
            acc[0][1] = __builtin_amdgcn_mfma_f32_16x16x32_bf16(a[0][ks], b1, acc[0][1], 0, 0, 0);
            acc[1][1] = __builtin_amdgcn_mfma_f32_16x16x32_bf16(a[1][ks], b1, acc[1][1], 0, 0, 0);
            acc[0][2] = __builtin_amdgcn_mfma_f32_16x16x32_bf16(a[0][ks], b2, acc[0][2], 0, 0, 0);
            acc[1][2] = __builtin_amdgcn_mfma_f32_16x16x32_bf16(a[1][ks], b2, acc[1][2], 0, 0, 0);
            acc[0][3] = __builtin_amdgcn_mfma_f32_16x16x32_bf16(a[0][ks], b3, acc[0][3], 0, 0, 0);
            acc[1][3] = __builtin_amdgcn_mfma_f32_16x16x32_bf16(a[1][ks], b3, acc[1][3], 0, 0, 0);
        }
        __syncthreads();
    }

    // ---- epilogue: M writes + fixed-shift exp sums ----
    // D layout: col = C + ct*16 + lr, row = R + hi*4 + i.
#pragma unroll
    for (int rb = 0; rb < 2; ++rb) {
        const int R = rb ? R1 : R0;
        if (useM) {
#pragma unroll
            for (int i = 0; i < 4; ++i) {
                size_t rg = (size_t)(R + hi * 4 + i) * L_CLS + C + lr;
                M[rg]      = acc[rb][0][i];
                M[rg + 16] = acc[rb][1][i];
                M[rg + 32] = acc[rb][2][i];
                M[rg + 48] = acc[rb][3][i];
            }
        }
        float p[4];
#pragma unroll
        for (int i = 0; i < 4; ++i) {
            p[i] = exp2f(acc[rb][0][i] * LOG2E - SHIFT)
                 + exp2f(acc[rb][1][i] * LOG2E - SHIFT)
                 + exp2f(acc[rb][2][i] * LOG2E - SHIFT)
                 + exp2f(acc[rb][3][i] * LOG2E - SHIFT);
        }
#pragma unroll
        for (int off = 1; off < 16; off <<= 1)
#pragma unroll
            for (int i = 0; i < 4; ++i) p[i] += __shfl_xor(p[i], off);
        if (lr == 0) {
#pragma unroll
            for (int i = 0; i < 4; ++i)
                psum[(R + hi * 4 + i) * NCHUNK + by] = p[i];
        }
    }

    // ---- epoch-free grid barrier (device-scope atomics ONLY) ----
    __threadfence();              // release: M/psum write-back device-wide
    __syncthreads();
    if (tid == 0) {
        unsigned r0 = __hip_atomic_load(rel, __ATOMIC_RELAXED, __HIP_MEMORY_SCOPE_AGENT);
        unsigned old = atomicAdd(cnt, 1u);
        if (((old + 1u) & (NWG - 1u)) == 0u) {
            atomicAdd(rel, 1u);                      // I'm the NWG-th arrival
        } else {
            unsigned guard = 0;
            while (__hip_atomic_load(rel, __ATOMIC_RELAXED, __HIP_MEMORY_SCOPE_AGENT) == r0
                   && ++guard < (1u << 16)) {}       // ~10 ms bound
        }
    }
    __syncthreads();
    __threadfence();              // acquire: invalidate L1/L2 before reading M/psum

    // ---- P3: scores (64 outputs per WG, threads 0..63) ----
    if (tid < 64) {
        int o = w * 64 + tid;
        if (o < NOUT) {
            int b = o / NT;
            int t = o - b * NT;
            int src = labels[b * T_SZ + t];
            int tgt = labels[b * T_SZ + t + 1];

            const float* pv = psum + src * NCHUNK;
            float S = 0.f;
#pragma unroll
            for (int c = 0; c < NCHUNK; ++c) S += pv[c];
            float lse = (log2f(S) + SHIFT) * LN2;

            float logit;
            if (useM) {
                logit = M[(size_t)src * L_CLS + tgt];
            } else {
                const f32x4* sp = reinterpret_cast<const f32x4*>(srcE + src * D_DIM);
                const f32x4* tp = reinterpret_cast<const f32x4*>(tgtE + tgt * D_DIM);
                float a2 = 0.f;
                for (int j = 0; j < D_DIM / 4; ++j) {
                    f32x4 sv = sp[j], tv = tp[j];
                    a2 += sv[0]*tv[0] + sv[1]*tv[1] + sv[2]*tv[2] + sv[3]*tv[3];
                }
                logit = a2;
            }
            out[o] = logit - lse;
        }
    }
}

// ------------------------------------------------------------------- launcher
extern "C" void kernel_launch(void* const* d_in, const int* in_sizes, int n_in,
                              void* d_out, int out_size, void* d_ws, size_t ws_size,
                              hipStream_t stream) {
    const int*   labels = (const int*)d_in[0];
    const float* srcE   = (const float*)d_in[1];
    const float* tgtE   = (const float*)d_in[2];
    float*       out    = (float*)d_out;

    unsigned* cnt = (unsigned*)d_ws;
    unsigned* rel = cnt + 1;
    float* psum = (float*)((char*)d_ws + 16);          // 256 KB
    float* M    = psum + L_CLS * NCHUNK;               // 16 MB

    size_t need = 16 + ((size_t)L_CLS * NCHUNK + (size_t)L_CLS * L_CLS) * sizeof(float);
    int useM = (ws_size >= need) ? 1 : 0;

    fused_crf<<<NWG, 256, 0, stream>>>(labels, srcE, tgtE, psum, M, cnt, rel, out, useM);
}

// Round 9
// 103.463 us; speedup vs baseline: 4401.9079x; 69.4489x over previous
//
#include <hip/hip_runtime.h>
#include <hip/hip_bf16.h>

#define L_CLS 2048
#define D_DIM 512
#define T_SZ  512
#define NT    511              // T-1 transitions per sequence
#define NOUT  (64 * NT)        // 32704
#define NCHUNK 16              // 128-col chunks
#define NWG   256              // grid (16,16); <= 512 capacity -> all co-resident
#define LDS_STRIDE 136         // 128 bf16 + pad -> 272 B rows
#define LOG2E 1.4426950408889634f
#define LN2   0.6931471805599453f
#define SHIFT 128.0f           // fixed exponent shift: sum 2^(x*log2e - SHIFT)

typedef __attribute__((ext_vector_type(8))) short bf16x8;
typedef __attribute__((ext_vector_type(4))) float f32x4;

static __device__ __forceinline__ short f2bf(float x) {
    return (short)__bfloat16_as_ushort(__float2bfloat16(x));
}

// One kernel (+ a 16-B memset node zeroing the barrier words each call):
//  P1 (WG w: bx=w>>4, by=w&15): 128x128 output tile. Stage 128-row T-chunk
//     K-slice (f32->bf16) in LDS; two 64-row S-blocks (bx, bx+16), 8 col-tiles.
//     B-frag ds_read once per 2 MFMAs. Write logits to M + fixed-shift exp
//     sums to psum. Square tiles: A+B re-read traffic 192->128 MB vs R8.
//  Grid barrier: cnt/rel zeroed by the memset node, so arrival old==NWG-1 is
//     provably the last WG (R8 bug: 0xAA-poisoned cnt made the releaser fire
//     at arrival #342). Release = agent-scope store; spin = agent-scope
//     acquire load (R7 bug: volatile spin never saw cross-XCD release).
//  P3: 128 outputs/WG: out = M[src,tgt] - (log2(sum psum[src,:])+SHIFT)*ln2.
__launch_bounds__(256, 2)
__global__ void fused_crf(const int* __restrict__ labels,
                          const float* __restrict__ srcE,
                          const float* __restrict__ tgtE,
                          float* psum, float* M,
                          unsigned* cnt, unsigned* rel,
                          float* __restrict__ out, int useM) {
    __shared__ __hip_bfloat16 Blds[128 * LDS_STRIDE];   // 34816 B

    const int w    = blockIdx.x;
    const int tid  = threadIdx.x;
    const int wave = tid >> 6;
    const int lane = tid & 63;
    const int lr   = lane & 15;
    const int hi   = lane >> 4;
    const int by   = w & 15;
    const int bx   = w >> 4;
    const int C    = by * 128;
    const int R0   = bx * 64 + wave * 16;            // row-block 0
    const int R1   = (bx + 16) * 64 + wave * 16;     // row-block 1

    f32x4 acc[2][8];
#pragma unroll
    for (int rb = 0; rb < 2; ++rb)
#pragma unroll
        for (int ct = 0; ct < 8; ++ct) acc[rb][ct] = (f32x4){0.f, 0.f, 0.f, 0.f};

#pragma unroll 1
    for (int s = 0; s < 4; ++s) {    // K-slices of 128
        // ---- stage 128 rows x 128 k of T chunk into LDS (f32 -> bf16) ----
#pragma unroll
        for (int i = 0; i < 8; ++i) {
            int p   = tid + 256 * i;         // 0..2047
            int row = p >> 4;                // 0..127
            int grp = p & 15;                // 8-elem group 0..15
            const f32x4* g = reinterpret_cast<const f32x4*>(
                tgtE + (C + row) * D_DIM + s * 128 + grp * 8);
            f32x4 x0 = g[0], x1 = g[1];
            bf16x8 v;
#pragma unroll
            for (int e = 0; e < 4; ++e) { v[e] = f2bf(x0[e]); v[e + 4] = f2bf(x1[e]); }
            *reinterpret_cast<bf16x8*>(&Blds[row * LDS_STRIDE + grp * 8]) = v;
        }
        __syncthreads();

        // ---- A fragments for BOTH row-blocks, this slice (regs) ----
        bf16x8 a[2][4];
#pragma unroll
        for (int rb = 0; rb < 2; ++rb) {
            const int R = rb ? R1 : R0;
            const float* arow = srcE + (R + lr) * D_DIM + s * 128 + hi * 8;
#pragma unroll
            for (int ks = 0; ks < 4; ++ks) {
                const f32x4* g = reinterpret_cast<const f32x4*>(arow + ks * 32);
                f32x4 x0 = g[0], x1 = g[1];
                bf16x8 v;
#pragma unroll
                for (int e = 0; e < 4; ++e) { v[e] = f2bf(x0[e]); v[e + 4] = f2bf(x1[e]); }
                a[rb][ks] = v;
            }
        }

        // ---- MFMAs: each B fragment read once, feeds both row-blocks ----
#pragma unroll
        for (int ks = 0; ks < 4; ++ks) {
            const int off = ks * 32 + hi * 8;
#pragma unroll
            for (int ct = 0; ct < 8; ++ct) {
                bf16x8 b = *reinterpret_cast<const bf16x8*>(
                    &Blds[(ct * 16 + lr) * LDS_STRIDE + off]);
                acc[0][ct] = __builtin_amdgcn_mfma_f32_16x16x32_bf16(a[0][ks], b, acc[0][ct], 0, 0, 0);
                acc[1][ct] = __builtin_amdgcn_mfma_f32_16x16x32_bf16(a[1][ks], b, acc[1][ct], 0, 0, 0);
            }
        }
        __syncthreads();
    }

    // ---- epilogue: M writes + fixed-shift exp sums ----
    // D layout: col = C + ct*16 + lr, row = R + hi*4 + i.
#pragma unroll
    for (int rb = 0; rb < 2; ++rb) {
        const int R = rb ? R1 : R0;
        if (useM) {
#pragma unroll
            for (int i = 0; i < 4; ++i) {
                size_t rg = (size_t)(R + hi * 4 + i) * L_CLS + C + lr;
#pragma unroll
                for (int ct = 0; ct < 8; ++ct)
                    M[rg + ct * 16] = acc[rb][ct][i];
            }
        }
        float p[4];
#pragma unroll
        for (int i = 0; i < 4; ++i) {
            p[i] = 0.f;
#pragma unroll
            for (int ct = 0; ct < 8; ++ct)
                p[i] += exp2f(acc[rb][ct][i] * LOG2E - SHIFT);
        }
#pragma unroll
        for (int off = 1; off < 16; off <<= 1)
#pragma unroll
            for (int i = 0; i < 4; ++i) p[i] += __shfl_xor(p[i], off);
        if (lr == 0) {
#pragma unroll
            for (int i = 0; i < 4; ++i)
                psum[(R + hi * 4 + i) * NCHUNK + by] = p[i];
        }
    }

    // ---- grid barrier (cnt/rel pre-zeroed by memset node this call) ----
    __threadfence();              // release: M/psum visible device-wide
    __syncthreads();
    if (tid == 0) {
        unsigned old = atomicAdd(cnt, 1u);
        if (old == NWG - 1u) {
            __hip_atomic_store(rel, 1u, __ATOMIC_RELEASE, __HIP_MEMORY_SCOPE_AGENT);
        } else {
            unsigned guard = 0;
            while (__hip_atomic_load(rel, __ATOMIC_ACQUIRE, __HIP_MEMORY_SCOPE_AGENT) == 0u
                   && ++guard < (1u << 13)) {}
        }
    }
    __syncthreads();
    __threadfence();              // acquire: drop stale lines before reading M/psum

    // ---- P3: scores (128 outputs per WG, threads 0..127) ----
    if (tid < 128) {
        int o = w * 128 + tid;
        if (o < NOUT) {
            int b = o / NT;
            int t = o - b * NT;
            int src = labels[b * T_SZ + t];
            int tgt = labels[b * T_SZ + t + 1];

            const f32x4* pv = reinterpret_cast<const f32x4*>(psum + src * NCHUNK);
            f32x4 sv = pv[0];
            f32x4 s1 = pv[1], s2 = pv[2], s3 = pv[3];
            float S = (sv[0]+sv[1]+sv[2]+sv[3]) + (s1[0]+s1[1]+s1[2]+s1[3])
                    + (s2[0]+s2[1]+s2[2]+s2[3]) + (s3[0]+s3[1]+s3[2]+s3[3]);
            float lse = (log2f(S) + SHIFT) * LN2;

            float logit;
            if (useM) {
                logit = M[(size_t)src * L_CLS + tgt];
            } else {
                const f32x4* sp = reinterpret_cast<const f32x4*>(srcE + src * D_DIM);
                const f32x4* tp = reinterpret_cast<const f32x4*>(tgtE + tgt * D_DIM);
                float a2 = 0.f;
                for (int j = 0; j < D_DIM / 4; ++j) {
                    f32x4 svv = sp[j], tvv = tp[j];
                    a2 += svv[0]*tvv[0] + svv[1]*tvv[1] + svv[2]*tvv[2] + svv[3]*tvv[3];
                }
                logit = a2;
            }
            out[o] = logit - lse;
        }
    }
}

// ------------------------------------------------------------------- launcher
extern "C" void kernel_launch(void* const* d_in, const int* in_sizes, int n_in,
                              void* d_out, int out_size, void* d_ws, size_t ws_size,
                              hipStream_t stream) {
    const int*   labels = (const int*)d_in[0];
    const float* srcE   = (const float*)d_in[1];
    const float* tgtE   = (const float*)d_in[2];
    float*       out    = (float*)d_out;

    unsigned* cnt = (unsigned*)d_ws;
    unsigned* rel = cnt + 1;
    float* psum = (float*)((char*)d_ws + 16);          // 128 KB
    float* M    = psum + L_CLS * NCHUNK;               // 16 MB

    size_t need = 16 + ((size_t)L_CLS * NCHUNK + (size_t)L_CLS * L_CLS) * sizeof(float);
    int useM = (ws_size >= need) ? 1 : 0;

    hipMemsetAsync(d_ws, 0, 16, stream);               // zero cnt/rel each call
    fused_crf<<<NWG, 256, 0, stream>>>(labels, srcE, tgtE, psum, M, cnt, rel, out, useM);
}

// Round 10
// 31.625 us; speedup vs baseline: 14401.0856x; 3.2716x over previous
//
#include <hip/hip_runtime.h>
#include <hip/hip_bf16.h>

#define L_CLS 2048
#define D_DIM 512
#define T_SZ  512
#define NT    511              // T-1 transitions per sequence
#define NOUT  (64 * NT)        // 32704
#define NCHUNK 16              // 128-col chunks
#define LDS_STRIDE 136         // 128 bf16 + pad -> 272 B rows
#define LOG2E 1.4426950408889634f
#define LN2   0.6931471805599453f
#define SHIFT 128.0f           // fixed exponent shift: sum 2^(x*log2e - SHIFT)

typedef __attribute__((ext_vector_type(8))) short bf16x8;
typedef __attribute__((ext_vector_type(4))) float f32x4;

static __device__ __forceinline__ short f2bf(float x) {
    return (short)__bfloat16_as_ushort(__float2bfloat16(x));
}

// ---------------------------------------------- fused conv + GEMM + exp-sums
// grid (16,16): blockIdx.y -> two 64-row S-blocks (bx, bx+16), blockIdx.x ->
// 128-col T-chunk. 128x128 output tile per WG: minimal re-read traffic
// (each table read 16x = 128 MB total, L2/L3-resident).
// Per K-slice of 128: stage 128 T-rows f32->bf16 into LDS (padded stride),
// A-frags for both row-blocks in regs, then MFMAs with each B fragment
// ds_read ONCE feeding both row-blocks. Epilogue: logits -> M, fixed-shift
// exp sums -> psum (valid: |logit| <~ 125, sum 2^(x*log2e-128) in f32 range).
// No cross-WG sync anywhere; every psum/M slot written every call.
__launch_bounds__(256)
__global__ void gemm_lse(const float* __restrict__ srcE,
                         const float* __restrict__ tgtE,
                         float* __restrict__ psum,
                         float* __restrict__ M, int useM) {
    __shared__ __hip_bfloat16 Blds[128 * LDS_STRIDE];   // 34816 B

    const int tid  = threadIdx.x;
    const int wave = tid >> 6;
    const int lane = tid & 63;
    const int lr   = lane & 15;
    const int hi   = lane >> 4;
    const int by   = blockIdx.x;
    const int bx   = blockIdx.y;
    const int C    = by * 128;
    const int R0   = bx * 64 + wave * 16;            // row-block 0
    const int R1   = (bx + 16) * 64 + wave * 16;     // row-block 1

    f32x4 acc[2][8];
#pragma unroll
    for (int rb = 0; rb < 2; ++rb)
#pragma unroll
        for (int ct = 0; ct < 8; ++ct) acc[rb][ct] = (f32x4){0.f, 0.f, 0.f, 0.f};

#pragma unroll 1
    for (int s = 0; s < 4; ++s) {    // K-slices of 128
        // ---- stage 128 rows x 128 k of T chunk into LDS (f32 -> bf16) ----
#pragma unroll
        for (int i = 0; i < 8; ++i) {
            int p   = tid + 256 * i;         // 0..2047
            int row = p >> 4;                // 0..127
            int grp = p & 15;                // 8-elem group 0..15
            const f32x4* g = reinterpret_cast<const f32x4*>(
                tgtE + (C + row) * D_DIM + s * 128 + grp * 8);
            f32x4 x0 = g[0], x1 = g[1];
            bf16x8 v;
#pragma unroll
            for (int e = 0; e < 4; ++e) { v[e] = f2bf(x0[e]); v[e + 4] = f2bf(x1[e]); }
            *reinterpret_cast<bf16x8*>(&Blds[row * LDS_STRIDE + grp * 8]) = v;
        }
        __syncthreads();

        // ---- A fragments for BOTH row-blocks, this slice (regs) ----
        bf16x8 a[2][4];
#pragma unroll
        for (int rb = 0; rb < 2; ++rb) {
            const int R = rb ? R1 : R0;
            const float* arow = srcE + (R + lr) * D_DIM + s * 128 + hi * 8;
#pragma unroll
            for (int ks = 0; ks < 4; ++ks) {
                const f32x4* g = reinterpret_cast<const f32x4*>(arow + ks * 32);
                f32x4 x0 = g[0], x1 = g[1];
                bf16x8 v;
#pragma unroll
                for (int e = 0; e < 4; ++e) { v[e] = f2bf(x0[e]); v[e + 4] = f2bf(x1[e]); }
                a[rb][ks] = v;
            }
        }

        // ---- MFMAs: each B fragment read once, feeds both row-blocks ----
#pragma unroll
        for (int ks = 0; ks < 4; ++ks) {
            const int off = ks * 32 + hi * 8;
#pragma unroll
            for (int ct = 0; ct < 8; ++ct) {
                bf16x8 b = *reinterpret_cast<const bf16x8*>(
                    &Blds[(ct * 16 + lr) * LDS_STRIDE + off]);
                acc[0][ct] = __builtin_amdgcn_mfma_f32_16x16x32_bf16(a[0][ks], b, acc[0][ct], 0, 0, 0);
                acc[1][ct] = __builtin_amdgcn_mfma_f32_16x16x32_bf16(a[1][ks], b, acc[1][ct], 0, 0, 0);
            }
        }
        __syncthreads();
    }

    // ---- epilogue: M writes + fixed-shift exp sums ----
    // D layout: col = C + ct*16 + lr, row = R + hi*4 + i.
#pragma unroll
    for (int rb = 0; rb < 2; ++rb) {
        const int R = rb ? R1 : R0;
        if (useM) {
#pragma unroll
            for (int i = 0; i < 4; ++i) {
                size_t rg = (size_t)(R + hi * 4 + i) * L_CLS + C + lr;
#pragma unroll
                for (int ct = 0; ct < 8; ++ct)
                    M[rg + ct * 16] = acc[rb][ct][i];
            }
        }
        float p[4];
#pragma unroll
        for (int i = 0; i < 4; ++i) {
            p[i] = 0.f;
#pragma unroll
            for (int ct = 0; ct < 8; ++ct)
                p[i] += exp2f(acc[rb][ct][i] * LOG2E - SHIFT);
        }
#pragma unroll
        for (int off = 1; off < 16; off <<= 1)
#pragma unroll
            for (int i = 0; i < 4; ++i) p[i] += __shfl_xor(p[i], off);
        if (lr == 0) {
#pragma unroll
            for (int i = 0; i < 4; ++i)
                psum[(R + hi * 4 + i) * NCHUNK + by] = p[i];
        }
    }
}

// -------------------------------------------------------------- gather scores
// one thread per output: out = M[src,tgt] - (log2(sum psum[src,:])+SHIFT)*ln2.
__launch_bounds__(256)
__global__ void scores_gather(const int* __restrict__ labels,
                              const float* __restrict__ psum,
                              const float* __restrict__ M,
                              float* __restrict__ out) {
    int o = blockIdx.x * 256 + threadIdx.x;
    if (o >= NOUT) return;
    int b = o / NT;
    int t = o - b * NT;
    int src = labels[b * T_SZ + t];
    int tgt = labels[b * T_SZ + t + 1];

    const f32x4* pv = reinterpret_cast<const f32x4*>(psum + src * NCHUNK);
    f32x4 s0 = pv[0], s1 = pv[1], s2 = pv[2], s3 = pv[3];
    float S = (s0[0]+s0[1]+s0[2]+s0[3]) + (s1[0]+s1[1]+s1[2]+s1[3])
            + (s2[0]+s2[1]+s2[2]+s2[3]) + (s3[0]+s3[1]+s3[2]+s3[3]);
    float lse = (log2f(S) + SHIFT) * LN2;
    out[o] = M[(size_t)src * L_CLS + tgt] - lse;
}

// -------------------------------------- fallback: dot-product scores (no M ws)
__launch_bounds__(256)
__global__ void scores_dot(const int* __restrict__ labels,
                           const float* __restrict__ srcE,
                           const float* __restrict__ tgtE,
                           const float* __restrict__ psum,
                           float* __restrict__ out) {
    const int wid  = blockIdx.x * 4 + (threadIdx.x >> 6);
    const int lane = threadIdx.x & 63;
    const int b = wid / NT;
    const int t = wid - b * NT;
    const int src = labels[b * T_SZ + t];
    const int tgt = labels[b * T_SZ + t + 1];

    const f32x4* sp = reinterpret_cast<const f32x4*>(srcE + src * D_DIM + lane * 8);
    const f32x4* tp = reinterpret_cast<const f32x4*>(tgtE + tgt * D_DIM + lane * 8);
    f32x4 s0 = sp[0], s1 = sp[1];
    f32x4 t0 = tp[0], t1 = tp[1];
    float acc = 0.f;
#pragma unroll
    for (int j = 0; j < 4; ++j) acc += s0[j] * t0[j] + s1[j] * t1[j];
    float ps = (lane < NCHUNK) ? psum[src * NCHUNK + lane] : 0.f;
#pragma unroll
    for (int off = 32; off; off >>= 1) {
        acc += __shfl_xor(acc, off);
        ps  += __shfl_xor(ps, off);
    }
    if (lane == 0) out[wid] = acc - (log2f(ps) + SHIFT) * LN2;
}

// ------------------------------------------------------------------- launcher
extern "C" void kernel_launch(void* const* d_in, const int* in_sizes, int n_in,
                              void* d_out, int out_size, void* d_ws, size_t ws_size,
                              hipStream_t stream) {
    const int*   labels = (const int*)d_in[0];
    const float* srcE   = (const float*)d_in[1];
    const float* tgtE   = (const float*)d_in[2];
    float*       out    = (float*)d_out;

    float* psum = (float*)d_ws;                        // 128 KB
    float* M    = psum + L_CLS * NCHUNK;               // 16 MB

    size_t need = ((size_t)L_CLS * NCHUNK + (size_t)L_CLS * L_CLS) * sizeof(float);
    int useM = (ws_size >= need) ? 1 : 0;

    gemm_lse<<<dim3(NCHUNK, 16), 256, 0, stream>>>(srcE, tgtE, psum, M, useM);
    if (useM)
        scores_gather<<<(NOUT + 255) / 256, 256, 0, stream>>>(labels, psum, M, out);
    else
        scores_dot<<<NOUT / 4, 256, 0, stream>>>(labels, srcE, tgtE, psum, out);
}